// Round 6
// baseline (654.917 us; speedup 1.0000x reference)
//
#include <hip/hip_runtime.h>

#define PI_D 3.14159265358979323846

// Layouts
//  x[l2,part]: (8192, 15, l2+1, 5, 16) fp32  n-stride = 1200*(l2+1)
//  w[l1,part]: (l1+1, 15, 5, 16, 16)  fp32   m 19200, t 1280, p 256, i 16, j 1
//  b[l,part]:  (1, l+1, 5, 16)        fp32   lr 80, p 16
//  out[l,part]:(8192, l+1, 5, 16) concat; base = 655360*(l+1)*(l+part)
//
// K (4800): l2{part'{kx{t{i(16)}}}} -> 300 blocks of 16; block offsets 0,30,90,180
// col (320): l{part{lr{j(16)}}};   offsets 0,32,96,192
// ws: G[16384] f32, then W'[p][col 320][K 4800] bf16 (15.36 MB)

typedef __attribute__((ext_vector_type(8))) short short8;
typedef __attribute__((ext_vector_type(4))) float f32x4;

struct Ptrs8 { const float* p[8]; };

__device__ __forceinline__ uint f2bf(float x){
  uint u = __float_as_uint(x);
  return ((u + 0x7fffu + ((u>>16)&1u)) >> 16);
}

__device__ __forceinline__ double dfact(int n){ double r=1.0; for(int i=2;i<=n;++i) r*=(double)i; return r; }

__device__ double cg_coef(int j1,int m1,int j2,int m2,int j3,int m3){
  if(m1+m2!=m3) return 0.0;
  if(j3<abs(j1-j2)||j3>j1+j2) return 0.0;
  if(abs(m1)>j1||abs(m2)>j2||abs(m3)>j3) return 0.0;
  double pre = sqrt((2.0*j3+1.0)*dfact(j3+j1-j2)*dfact(j3-j1+j2)*dfact(j1+j2-j3)/dfact(j1+j2+j3+1));
  pre *= sqrt(dfact(j3+m3)*dfact(j3-m3)*dfact(j1-m1)*dfact(j1+m1)*dfact(j2-m2)*dfact(j2+m2));
  int kmin = max(0,max(j2-j3-m1,j1-j3+m2));
  int kmax = min(j1+j2-j3,min(j1-m1,j2+m2));
  double s=0.0;
  for(int k=kmin;k<=kmax;++k){
    double d = dfact(k)*dfact(j1+j2-j3-k)*dfact(j1-m1-k)*dfact(j2+m2-k)*dfact(j3-j2+m1+k)*dfact(j3-j1-m2+k);
    s += ((k&1)?-1.0:1.0)/d;
  }
  return pre*s;
}

__device__ __forceinline__ int gidx(int l,int l2,int combo,int lr,int kx,int l1,int m){
  return ((((((l*4+l2)*4+combo)*4+lr)*4+kx)*4+l1)*4+m);
}

__global__ void g_kernel(float* __restrict__ G){
  int tid = threadIdx.x;
  for(int e=tid;e<16384;e+=blockDim.x) G[e]=0.0f;
  __syncthreads();
  int trip = tid >> 4;
  int sub  = tid & 15;
  int lr = sub >> 2, m = sub & 3;
  int idx=0;
  for(int l=0;l<4;l++)for(int l1=0;l1<4;l1++){
    int lo=abs(l-l1), hi=min(3,l+l1);
    for(int l2=lo;l2<=hi;l2++){
      if(idx==trip && lr<=l && m<=l1){
        double c = 8.0*PI_D*PI_D/(2.0*l1+1.0)
                 * sqrt((2.0*l+1.0)*(2.0*l1+1.0)/(4.0*PI_D*(2.0*l2+1.0)))
                 * cg_coef(l,0,l1,0,l2,0);
        if(lr+m<=l2){
          float f = (float)(c * cg_coef(l,lr,l1,m,l2,lr+m) * ((m&1)?-1.0:1.0));
          G[gidx(l,l2,0,lr,lr+m,l1,m)] += f;
          G[gidx(l,l2,1,lr,lr+m,l1,m)] -= f;
          G[gidx(l,l2,2,lr,lr+m,l1,m)] += f;
          G[gidx(l,l2,3,lr,lr+m,l1,m)] += f;
        }
        if(m>0 && abs(lr-m)<=l2){
          if(lr-m>=0){
            float f = (float)(c * cg_coef(l,lr,l1,-m,l2,lr-m) * ((l1&1)?-1.0:1.0));
            G[gidx(l,l2,0,lr,lr-m,l1,m)] += f;
            G[gidx(l,l2,1,lr,lr-m,l1,m)] += f;
            G[gidx(l,l2,2,lr,lr-m,l1,m)] -= f;
            G[gidx(l,l2,3,lr,lr-m,l1,m)] += f;
          } else {
            float f = (float)(c * (((m-lr)&1)?-1.0:1.0) * (((l1+l2)&1)?-1.0:1.0)
                              * cg_coef(l,lr,l1,-m,l2,lr-m));
            G[gidx(l,l2,0,lr,m-lr,l1,m)] += f;
            G[gidx(l,l2,1,lr,m-lr,l1,m)] -= f;
            G[gidx(l,l2,2,lr,m-lr,l1,m)] -= f;
            G[gidx(l,l2,3,lr,m-lr,l1,m)] -= f;
          }
        }
      }
      idx++;
    }
  }
}

__device__ __forceinline__ void decode_kb(int kb,int& l2,int& partp,int& kx,int& t){
  int kbo;
  if(kb<30){l2=0;kbo=0;} else if(kb<90){l2=1;kbo=30;} else if(kb<180){l2=2;kbo=90;} else {l2=3;kbo=180;}
  int rem = kb-kbo;
  int per = (l2+1)*15;
  partp = rem/per;
  int q = rem%per;
  kx = q/15; t = q%15;
}

__device__ __forceinline__ void decode_col(int col,int& l,int& part,int& lr,int& j){
  int co;
  if(col<32){l=0;co=0;} else if(col<96){l=1;co=32;} else if(col<192){l=2;co=96;} else {l=3;co=192;}
  int cr = col-co; int per=(l+1)*16;
  part = cr/per; int q = cr%per; lr = q>>4; j = q&15;
}

// W'[p][col][K] bf16
__global__ void w_kernel(const float* __restrict__ G, Ptrs8 wp, ushort* __restrict__ W){
  long e = (long)blockIdx.x*256 + threadIdx.x;
  if(e >= 5L*320*4800) return;
  int K = (int)(e%4800); long r = e/4800; int col = (int)(r%320); int p = (int)(r/320);
  int i = K & 15; int kb = K >> 4;
  int l2,partp,kx,t; decode_kb(kb,l2,partp,kx,t);
  int l,part,lr,j; decode_col(col,l,part,lr,j);
  int combo = (part==0) ? (partp==0?0:1) : (partp==0?2:3);
  int wpart = (combo==0||combo==3)?0:1;
  int mstart = wpart?1:0;
  int woff = t*1280 + p*256 + i*16 + j;
  float acc=0.f;
  for(int l1=0;l1<4;l1++){
    const float* wptr = wp.p[l1*2+wpart];
    int gb = ((((l*4+l2)*4+combo)*4+lr)*4+kx)*16 + l1*4;
    for(int m=mstart;m<=l1;m++){
      float g = G[gb+m];
      if(g!=0.f) acc += g * wptr[m*19200 + woff];
    }
  }
  W[e] = (ushort)f2bf(acc);
}

// ---------------- GEMM: out[8192x320] = X[8192x4800] * W'[4800x320], per p ----
// OCCUPANCY EXPERIMENT: 32-row tiles -> grid 1280 (5 blocks/CU of work),
// __launch_bounds__(256,4) (target 4 blocks/CU resident = 16 waves/CU).
// Raw barriers (loads cross); B single-buffered (issued first each step, L2);
// A reg-staged depth-2. LDS 8KB (two 4KB swizzled 32x64 bf16 tiles).

__device__ __forceinline__ void a_issue(const Ptrs8& xp,int p,int n0,int kt,int w,int lane,float4* v){
  int kb = kt*4 + w;                       // wave w loads K-subblock w of the 64-K tile
  int l2,partp,kx,t; decode_kb(kb,l2,partp,kx,t);
  const float* xb = xp.p[l2*2+partp];
  int nstr = 1200*(l2+1);
  const float* base = xb + (long)(n0 + (lane>>2))*nstr + (t*(l2+1)+kx)*80 + p*16 + (lane&3)*4;
  long step = (long)16*nstr;
  #pragma unroll
  for(int s=0;s<2;++s) v[s] = *(const float4*)(base + s*step);
}

__device__ __forceinline__ void a_store(ushort* As,int w,int lane,const float4* v){
  int rsub = lane>>2, c4 = (lane&3)*4;
  #pragma unroll
  for(int s=0;s<2;++s){
    int row = s*16 + rsub;
    int e = row*64 + ((w*16 + c4) ^ ((row&7)<<3));
    uint2 d;
    d.x = f2bf(v[s].x) | (f2bf(v[s].y)<<16);
    d.y = f2bf(v[s].z) | (f2bf(v[s].w)<<16);
    *(uint2*)(As + e) = d;
  }
}

__device__ __forceinline__ void b_load(const ushort* Wp,int w,int lane,int kt,short8* b){
  const ushort* q = Wp + (long)(w*80 + (lane&15))*4800 + kt*64 + ((lane>>4)*8);
  #pragma unroll
  for(int ks=0;ks<2;++ks)
    #pragma unroll
    for(int ni=0;ni<5;++ni)
      b[ks*5+ni] = *(const short8*)(q + (long)ni*16*4800 + ks*32);
}

__device__ __forceinline__ void do_mfma(const ushort* As,int lane,const short8* b,f32x4 acc[2][5]){
  #pragma unroll
  for(int ks=0;ks<2;++ks){
    short8 af[2];
    #pragma unroll
    for(int mi=0;mi<2;++mi){
      int row = mi*16 + (lane&15);
      int e = row*64 + (((ks*32) + (lane>>4)*8) ^ ((row&7)<<3));
      af[mi] = *(const short8*)(As + e);
    }
    #pragma unroll
    for(int mi=0;mi<2;++mi)
      #pragma unroll
      for(int ni=0;ni<5;++ni)
        acc[mi][ni] = __builtin_amdgcn_mfma_f32_16x16x32_bf16(af[mi], b[ks*5+ni], acc[mi][ni], 0,0,0);
  }
}

#define RAW_BAR() do { \
  asm volatile("s_waitcnt lgkmcnt(0)" ::: "memory"); \
  __builtin_amdgcn_s_barrier(); \
  __builtin_amdgcn_sched_barrier(0); \
} while(0)

__global__ __launch_bounds__(256,4) void gemm_kernel(Ptrs8 xp, const ushort* __restrict__ Wb,
                                                     Ptrs8 bp, float* __restrict__ out){
  __shared__ ushort As[2][2048];
  const int tid = threadIdx.x;
  const int lane = tid & 63;
  const int w = tid >> 6;
  // XCD-chunked bijective swizzle: 1280 blocks, 8 XCDs, chunk 160
  int orig = blockIdx.x;
  int wg = (orig & 7)*160 + (orig >> 3);
  const int p = wg / 256;
  const int nb = wg % 256;
  const int n0 = nb*32;
  const ushort* Wp = Wb + (long)p*320*4800;

  f32x4 acc[2][5] = {};
  float4 avA[2], avB[2];   // a(t): stored at step t-1; depth-2 issue (a(kt+2) at step kt)
  short8 bf[10];           // B single-buffered: b(kt) issued & consumed in step kt

  // prologue: tile0 -> LDS, issue a(1)
  {
    float4 t0[2];
    a_issue(xp, p, n0, 0, w, lane, t0);
    a_store(&As[0][0], w, lane, t0);
  }
  a_issue(xp, p, n0, 1, w, lane, avA);
  RAW_BAR();

  // step kt: b_load(kt) FIRST; a_issue(kt+2); a_store a(kt+1); mfma tile kt.
#define STEP(kt, avIn, avOut) do { \
    b_load(Wp, w, lane, (kt), bf); \
    if((kt) < 73) a_issue(xp, p, n0, (kt)+2, w, lane, avOut); \
    if((kt) < 74) a_store(&As[((kt)+1)&1][0], w, lane, avIn); \
    __builtin_amdgcn_s_setprio(1); \
    do_mfma(&As[(kt)&1][0], lane, bf, acc); \
    __builtin_amdgcn_s_setprio(0); \
    RAW_BAR(); \
  } while(0)

  #pragma unroll 1
  for(int kt=0; kt<74; kt+=2){
    STEP(kt,   avA, avB);
    STEP(kt+1, avB, avA);
  }
  STEP(74, avA, avB);
#undef STEP

  // epilogue
  int j = lane & 15, rg = (lane>>4)*4;
  #pragma unroll
  for(int ni=0;ni<5;++ni){
    int col16 = w*5 + ni;
    int l, part, lr;
    if(col16<2){l=0;part=col16;lr=0;}
    else if(col16<6){int c=col16-2;l=1;part=c>>1;lr=c&1;}
    else if(col16<12){int c=col16-6;l=2;part=(c>=3);lr=part?(c-3):c;}
    else {int c=col16-12;l=3;part=c>>2;lr=c&3;}
    float bv = 0.f;
    if(!(part==1 && lr==0)) bv = bp.p[l*2+part][lr*80 + p*16 + j];
    long base = 655360L*(l+1)*(l+part);
    int nst = (l+1)*80;
    long ioff = base + lr*80 + p*16 + j;
    #pragma unroll
    for(int mi=0;mi<2;++mi){
      int n = n0 + mi*16 + rg;
      #pragma unroll
      for(int r=0;r<4;++r)
        out[ioff + (long)(n+r)*nst] = acc[mi][ni][r] + bv;
    }
  }
}

extern "C" void kernel_launch(void* const* d_in, const int* in_sizes, int n_in,
                              void* d_out, int out_size, void* d_ws, size_t ws_size,
                              hipStream_t stream){
  Ptrs8 xp, wp, bp;
  for(int i=0;i<8;i++){
    xp.p[i] = (const float*)d_in[i];
    wp.p[i] = (const float*)d_in[8+i];
    bp.p[i] = (const float*)d_in[16+i];
  }
  float* G = (float*)d_ws;
  ushort* W = (ushort*)((char*)d_ws + 16384*4);
  g_kernel<<<dim3(1), dim3(576), 0, stream>>>(G);
  w_kernel<<<dim3(30000), dim3(256), 0, stream>>>(G, wp, W);
  gemm_kernel<<<dim3(1280), dim3(256), 0, stream>>>(xp, W, bp, (float*)d_out);
}

// Round 7
// 482.813 us; speedup vs baseline: 1.3565x; 1.3565x over previous
//
#include <hip/hip_runtime.h>

#define PI_D 3.14159265358979323846

// Layouts
//  x[l2,part]: (8192, 15, l2+1, 5, 16) fp32  n-stride = 1200*(l2+1)
//  w[l1,part]: (l1+1, 15, 5, 16, 16)  fp32   m 19200, t 1280, p 256, i 16, j 1
//  b[l,part]:  (1, l+1, 5, 16)        fp32   lr 80, p 16
//  out[l,part]:(8192, l+1, 5, 16) concat; base = 655360*(l+1)*(l+part)
//
// K (4800): l2{part'{kx{t{i(16)}}}} -> 300 blocks of 16; block offsets 0,30,90,180
// col (320): l{part{lr{j(16)}}};   offsets 0,32,96,192
// ws: G[16384] f32, then W'[p][col 320][K 4800] bf16 (15.36 MB)

typedef __attribute__((ext_vector_type(8))) short short8;
typedef __attribute__((ext_vector_type(4))) float f32x4;

struct Ptrs8 { const float* p[8]; };

__device__ __forceinline__ ushort f2bf(float x){
  uint u = __float_as_uint(x);
  return (ushort)((u + 0x7fffu + ((u>>16)&1u)) >> 16);
}

__device__ __forceinline__ double dfact(int n){ double r=1.0; for(int i=2;i<=n;++i) r*=(double)i; return r; }

__device__ double cg_coef(int j1,int m1,int j2,int m2,int j3,int m3){
  if(m1+m2!=m3) return 0.0;
  if(j3<abs(j1-j2)||j3>j1+j2) return 0.0;
  if(abs(m1)>j1||abs(m2)>j2||abs(m3)>j3) return 0.0;
  double pre = sqrt((2.0*j3+1.0)*dfact(j3+j1-j2)*dfact(j3-j1+j2)*dfact(j1+j2-j3)/dfact(j1+j2+j3+1));
  pre *= sqrt(dfact(j3+m3)*dfact(j3-m3)*dfact(j1-m1)*dfact(j1+m1)*dfact(j2-m2)*dfact(j2+m2));
  int kmin = max(0,max(j2-j3-m1,j1-j3+m2));
  int kmax = min(j1+j2-j3,min(j1-m1,j2+m2));
  double s=0.0;
  for(int k=kmin;k<=kmax;++k){
    double d = dfact(k)*dfact(j1+j2-j3-k)*dfact(j1-m1-k)*dfact(j2+m2-k)*dfact(j3-j2+m1+k)*dfact(j3-j1-m2+k);
    s += ((k&1)?-1.0:1.0)/d;
  }
  return pre*s;
}

__device__ __forceinline__ int gidx(int l,int l2,int combo,int lr,int kx,int l1,int m){
  return ((((((l*4+l2)*4+combo)*4+lr)*4+kx)*4+l1)*4+m);
}

__global__ void g_kernel(float* __restrict__ G){
  int tid = threadIdx.x;
  for(int e=tid;e<16384;e+=blockDim.x) G[e]=0.0f;
  __syncthreads();
  int trip = tid >> 4;
  int sub  = tid & 15;
  int lr = sub >> 2, m = sub & 3;
  int idx=0;
  for(int l=0;l<4;l++)for(int l1=0;l1<4;l1++){
    int lo=abs(l-l1), hi=min(3,l+l1);
    for(int l2=lo;l2<=hi;l2++){
      if(idx==trip && lr<=l && m<=l1){
        double c = 8.0*PI_D*PI_D/(2.0*l1+1.0)
                 * sqrt((2.0*l+1.0)*(2.0*l1+1.0)/(4.0*PI_D*(2.0*l2+1.0)))
                 * cg_coef(l,0,l1,0,l2,0);
        if(lr+m<=l2){
          float f = (float)(c * cg_coef(l,lr,l1,m,l2,lr+m) * ((m&1)?-1.0:1.0));
          G[gidx(l,l2,0,lr,lr+m,l1,m)] += f;
          G[gidx(l,l2,1,lr,lr+m,l1,m)] -= f;
          G[gidx(l,l2,2,lr,lr+m,l1,m)] += f;
          G[gidx(l,l2,3,lr,lr+m,l1,m)] += f;
        }
        if(m>0 && abs(lr-m)<=l2){
          if(lr-m>=0){
            float f = (float)(c * cg_coef(l,lr,l1,-m,l2,lr-m) * ((l1&1)?-1.0:1.0));
            G[gidx(l,l2,0,lr,lr-m,l1,m)] += f;
            G[gidx(l,l2,1,lr,lr-m,l1,m)] += f;
            G[gidx(l,l2,2,lr,lr-m,l1,m)] -= f;
            G[gidx(l,l2,3,lr,lr-m,l1,m)] += f;
          } else {
            float f = (float)(c * (((m-lr)&1)?-1.0:1.0) * (((l1+l2)&1)?-1.0:1.0)
                              * cg_coef(l,lr,l1,-m,l2,lr-m));
            G[gidx(l,l2,0,lr,m-lr,l1,m)] += f;
            G[gidx(l,l2,1,lr,m-lr,l1,m)] -= f;
            G[gidx(l,l2,2,lr,m-lr,l1,m)] -= f;
            G[gidx(l,l2,3,lr,m-lr,l1,m)] -= f;
          }
        }
      }
      idx++;
    }
  }
}

__device__ __forceinline__ void decode_kb(int kb,int& l2,int& partp,int& kx,int& t){
  int kbo;
  if(kb<30){l2=0;kbo=0;} else if(kb<90){l2=1;kbo=30;} else if(kb<180){l2=2;kbo=90;} else {l2=3;kbo=180;}
  int rem = kb-kbo;
  int per = (l2+1)*15;
  partp = rem/per;
  int q = rem%per;
  kx = q/15; t = q%15;
}

__device__ __forceinline__ void decode_col(int col,int& l,int& part,int& lr,int& j){
  int co;
  if(col<32){l=0;co=0;} else if(col<96){l=1;co=32;} else if(col<192){l=2;co=96;} else {l=3;co=192;}
  int cr = col-co; int per=(l+1)*16;
  part = cr/per; int q = cr%per; lr = q>>4; j = q&15;
}

// W'[p][col][K] bf16
__global__ void w_kernel(const float* __restrict__ G, Ptrs8 wp, ushort* __restrict__ W){
  long e = (long)blockIdx.x*256 + threadIdx.x;
  if(e >= 5L*320*4800) return;
  int K = (int)(e%4800); long r = e/4800; int col = (int)(r%320); int p = (int)(r/320);
  int i = K & 15; int kb = K >> 4;
  int l2,partp,kx,t; decode_kb(kb,l2,partp,kx,t);
  int l,part,lr,j; decode_col(col,l,part,lr,j);
  int combo = (part==0) ? (partp==0?0:1) : (partp==0?2:3);
  int wpart = (combo==0||combo==3)?0:1;
  int mstart = wpart?1:0;
  int woff = t*1280 + p*256 + i*16 + j;
  float acc=0.f;
  for(int l1=0;l1<4;l1++){
    const float* wptr = wp.p[l1*2+wpart];
    int gb = ((((l*4+l2)*4+combo)*4+lr)*4+kx)*16 + l1*4;
    for(int m=mstart;m<=l1;m++){
      float g = G[gb+m];
      if(g!=0.f) acc += g * wptr[m*19200 + woff];
    }
  }
  W[e] = f2bf(acc);
}

// ---------------- GEMM: out[8192x320] = X[8192x4800] * W'[4800x320], per p ----
// EXACT R2 structure (best so far: 437 us): 64-row tile x 320 cols, 4 waves,
// A 64x64 bf16 LDS dbuf XOR-swizzled, B direct global b128, __syncthreads.
// ONLY change: block mapping. The 5 p-blocks of one n-tile are placed on the
// SAME XCD, launched back-to-back -> co-resident & in loose lockstep. Their
// 64-B X-chunks (offset p*64B) merge in the XCD L2 into 320-B DRAM runs,
// attacking the DRAM-activation bound (all rounds cap at 1.1-1.9 TB/s with
// 64-B strided chunks).

__device__ __forceinline__ void a_load(const Ptrs8& xp, int p, int n0, int kt, int w, int lane, float4* v){
  int kb = kt*4 + w;
  int l2,partp,kx,t; decode_kb(kb,l2,partp,kx,t);
  const float* xb = xp.p[l2*2+partp];
  int nstr = 1200*(l2+1);
  const float* base = xb + (long)(n0 + (lane>>2))*nstr + (t*(l2+1)+kx)*80 + p*16 + (lane&3)*4;
  long step = (long)16*nstr;
  #pragma unroll
  for(int s=0;s<4;++s) v[s] = *(const float4*)(base + s*step);
}

__device__ __forceinline__ void a_store(ushort* As, int w, int lane, const float4* v){
  int rsub = lane>>2, c4 = (lane&3)*4;
  #pragma unroll
  for(int s=0;s<4;++s){
    int row = s*16 + rsub;
    int e = row*64 + ((w*16 + c4) ^ ((row&7)<<3));
    uint2 d;
    d.x = (uint)f2bf(v[s].x) | ((uint)f2bf(v[s].y)<<16);
    d.y = (uint)f2bf(v[s].z) | ((uint)f2bf(v[s].w)<<16);
    *(uint2*)(As + e) = d;
  }
}

__device__ __forceinline__ void b_load(const ushort* Wp, int w, int lane, int kt, short8* b){
  const ushort* q = Wp + (long)(w*80 + (lane&15))*4800 + kt*64 + ((lane>>4)*8);
  #pragma unroll
  for(int ks=0;ks<2;++ks)
    #pragma unroll
    for(int ni=0;ni<5;++ni)
      b[ks*5+ni] = *(const short8*)(q + (long)ni*16*4800 + ks*32);
}

__device__ __forceinline__ void do_mfma(const ushort* As, int lane, const short8* b, f32x4 acc[4][5]){
  #pragma unroll
  for(int ks=0;ks<2;++ks){
    short8 af[4];
    #pragma unroll
    for(int mi=0;mi<4;++mi){
      int row = mi*16 + (lane&15);
      int e = row*64 + (((ks*32) + (lane>>4)*8) ^ ((row&7)<<3));
      af[mi] = *(const short8*)(As + e);
    }
    #pragma unroll
    for(int mi=0;mi<4;++mi)
      #pragma unroll
      for(int ni=0;ni<5;++ni)
        acc[mi][ni] = __builtin_amdgcn_mfma_f32_16x16x32_bf16(af[mi], b[ks*5+ni], acc[mi][ni], 0,0,0);
  }
}

__global__ __launch_bounds__(256,2) void gemm_kernel(Ptrs8 xp, const ushort* __restrict__ Wb,
                                                     Ptrs8 bp, float* __restrict__ out){
  __shared__ ushort As[2][4096];
  const int tid = threadIdx.x;
  const int lane = tid & 63;
  const int w = tid >> 6;
  // p-grouped XCD mapping: assume xcd = orig%8 (round-robin dispatch).
  // XCD x receives, in order: (p=0..4, nb=x), (p=0..4, nb=8+x), ...
  // -> the 5 p-blocks of each n-tile are same-XCD, temporally adjacent.
  int orig = blockIdx.x;
  int x = orig & 7, q = orig >> 3;
  const int p = q % 5;
  const int nb = (q/5)*8 + x;          // bijective: orig <-> (p, nb)
  const int n0 = nb*64;
  const ushort* Wp = Wb + (long)p*320*4800;

  f32x4 acc[4][5] = {};
  float4 av[4];
  short8 bfr[10];

  a_load(xp, p, n0, 0, w, lane, av);
  a_store(&As[0][0], w, lane, av);
  b_load(Wp, w, lane, 0, bfr);
  __syncthreads();

  int buf = 0;
  #pragma unroll 1
  for(int kt=0;kt<74;++kt){
    a_load(xp, p, n0, kt+1, w, lane, av);       // HBM prefetch (next tile)
    do_mfma(&As[buf][0], lane, bfr, acc);       // compute current
    b_load(Wp, w, lane, kt+1, bfr);             // B for next (L2)
    a_store(&As[buf^1][0], w, lane, av);        // cvt + LDS write (next buffer)
    __syncthreads();
    buf ^= 1;
  }
  do_mfma(&As[buf][0], lane, bfr, acc);

  // epilogue
  int j = lane & 15, rg = (lane>>4)*4;
  #pragma unroll
  for(int ni=0;ni<5;++ni){
    int col16 = w*5 + ni;
    int l, part, lr;
    if(col16<2){l=0;part=col16;lr=0;}
    else if(col16<6){int c=col16-2;l=1;part=c>>1;lr=c&1;}
    else if(col16<12){int c=col16-6;l=2;part=(c>=3);lr=part?(c-3):c;}
    else {int c=col16-12;l=3;part=c>>2;lr=c&3;}
    float bv = 0.f;
    if(!(part==1 && lr==0)) bv = bp.p[l*2+part][lr*80 + p*16 + j];
    long base = 655360L*(l+1)*(l+part);
    int nst = (l+1)*80;
    long ioff = base + lr*80 + p*16 + j;
    #pragma unroll
    for(int mi=0;mi<4;++mi){
      int n = n0 + mi*16 + rg;
      #pragma unroll
      for(int r=0;r<4;++r)
        out[ioff + (long)(n+r)*nst] = acc[mi][ni][r] + bv;
    }
  }
}

extern "C" void kernel_launch(void* const* d_in, const int* in_sizes, int n_in,
                              void* d_out, int out_size, void* d_ws, size_t ws_size,
                              hipStream_t stream){
  Ptrs8 xp, wp, bp;
  for(int i=0;i<8;i++){
    xp.p[i] = (const float*)d_in[i];
    wp.p[i] = (const float*)d_in[8+i];
    bp.p[i] = (const float*)d_in[16+i];
  }
  float* G = (float*)d_ws;
  ushort* W = (ushort*)((char*)d_ws + 16384*4);
  g_kernel<<<dim3(1), dim3(576), 0, stream>>>(G);
  w_kernel<<<dim3(30000), dim3(256), 0, stream>>>(G, wp, W);
  gemm_kernel<<<dim3(640), dim3(256), 0, stream>>>(xp, W, bp, (float*)d_out);
}